// Round 2
// baseline (223.233 us; speedup 1.0000x reference)
//
#include <hip/hip_runtime.h>
#include <math.h>

#define TPB 256

using v4 = __attribute__((ext_vector_type(4))) float;

__global__ __launch_bounds__(TPB) void geo_kernel(const float* __restrict__ coords,
                                                  float* __restrict__ out, int n) {
    // rows [base-1, base+256] -> 258 rows = 774 floats
    __shared__ float s_c[3 * 258];     // ~3 KB
    __shared__ float s_ang[TPB * 3];   // 3 KB
    __shared__ float s_frm[TPB * 9];   // 9 KB

    const int tid  = threadIdx.x;
    const int base = blockIdx.x * TPB;
    const int r    = base + tid;

    // ---- cooperative, coalesced coord staging ----
    const long g0   = 3L * base - 3;
    const long gmax = 3L * n - 1;
    #pragma unroll
    for (int i = tid; i < 3 * 258; i += TPB) {
        long g = g0 + i;
        g = g < 0 ? 0 : (g > gmax ? gmax : g);
        s_c[i] = coords[g];
    }
    __syncthreads();

    if (r < n) {
        // frame row: rows 0 / n-1 duplicate rows 1 / n-2
        int rr = r < 1 ? 1 : (r > n - 2 ? n - 2 : r);
        int lrow = rr - base + 1;              // local row index of center
        const float* p = s_c + 3 * (lrow - 1); // rows lrow-1 .. lrow+1

        float d1x = p[3] - p[0], d1y = p[4] - p[1], d1z = p[5] - p[2];
        float d2x = p[6] - p[3], d2y = p[7] - p[4], d2z = p[8] - p[5];

        // v = d * rsqrt(|d|^2)  (ref: d/(|d|+1e-10); equal to ~1e-7 for |d|~1)
        float inv1 = __builtin_amdgcn_rsqf(d1x * d1x + d1y * d1y + d1z * d1z + 1e-20f);
        float v1x = d1x * inv1, v1y = d1y * inv1, v1z = d1z * inv1;

        float inv2 = __builtin_amdgcn_rsqf(d2x * d2x + d2y * d2y + d2z * d2z + 1e-20f);
        float v2x = d2x * inv2, v2y = d2y * inv2, v2z = d2z * inv2;

        float dotv   = v1x * v2x + v1y * v2y + v1z * v2z;
        float cosang = fminf(1.0f, fmaxf(-1.0f, dotv));

        // acos via A&S 4.4.45: acos(x) ~ sqrt(1-x)*poly(x), x in [0,1]; err < 6.7e-5
        float ax   = fabsf(cosang);
        float sq   = __builtin_amdgcn_sqrtf(1.0f - ax);
        float poly = 1.5707288f + ax * (-0.2121144f + ax * (0.0742610f + ax * (-0.0187293f)));
        float rpos = sq * poly;
        float ang  = cosang >= 0.0f ? rpos : (3.14159265358979f - rpos);
        if (r == 0 || r == n - 1) ang = 0.0f;

        // Gram-Schmidt (proj uses UNclamped dot, as in the reference)
        float tx = v2x - dotv * v1x, ty = v2y - dotv * v1y, tz = v2z - dotv * v1z;
        float invt = __builtin_amdgcn_rsqf(tx * tx + ty * ty + tz * tz + 1e-20f);
        float e2x = tx * invt, e2y = ty * invt, e2z = tz * invt;

        float e3x = v1y * e2z - v1z * e2y;
        float e3y = v1z * e2x - v1x * e2z;
        float e3z = v1x * e2y - v1y * e2x;

        s_ang[tid * 3 + 0] = ang;
        s_ang[tid * 3 + 1] = ang;
        s_ang[tid * 3 + 2] = ang;

        float* f = s_frm + tid * 9;
        f[0] = v1x; f[1] = v1y; f[2] = v1z;
        f[3] = e2x; f[4] = e2y; f[5] = e2z;
        f[6] = e3x; f[7] = e3y; f[8] = e3z;
    }
    __syncthreads();

    float* angles = out;                     // n*3 floats
    float* frames = out + (size_t)n * 3;     // n*9 floats

    int valid = n - base;
    if (valid > TPB) valid = TPB;

    if (valid == TPB) {
        // coalesced nontemporal float4 flush; block byte offsets 3072/9216 -> 16B aligned
        v4*       ga = (v4*)(angles + (size_t)base * 3);
        const v4* sa = (const v4*)s_ang;
        if (tid < (TPB * 3) / 4)
            __builtin_nontemporal_store(sa[tid], &ga[tid]);        // 192 x float4

        v4*       gf = (v4*)(frames + (size_t)base * 9);
        const v4* sf = (const v4*)s_frm;
        __builtin_nontemporal_store(sf[tid],       &gf[tid]);      // 576 x float4
        __builtin_nontemporal_store(sf[tid + 256], &gf[tid + 256]);
        if (tid < 64)
            __builtin_nontemporal_store(sf[tid + 512], &gf[tid + 512]);
    } else {
        if (r < n) {
            angles[(size_t)r * 3 + 0] = s_ang[tid * 3 + 0];
            angles[(size_t)r * 3 + 1] = s_ang[tid * 3 + 1];
            angles[(size_t)r * 3 + 2] = s_ang[tid * 3 + 2];
            for (int k = 0; k < 9; ++k)
                frames[(size_t)r * 9 + k] = s_frm[tid * 9 + k];
        }
    }
}

extern "C" void kernel_launch(void* const* d_in, const int* in_sizes, int n_in,
                              void* d_out, int out_size, void* d_ws, size_t ws_size,
                              hipStream_t stream) {
    const float* coords = (const float*)d_in[0];
    float*       out    = (float*)d_out;
    int n = in_sizes[0] / 3;
    int blocks = (n + TPB - 1) / TPB;
    hipLaunchKernelGGL(geo_kernel, dim3(blocks), dim3(TPB), 0, stream, coords, out, n);
}

// Round 3
// 221.733 us; speedup vs baseline: 1.0068x; 1.0068x over previous
//
#include <hip/hip_runtime.h>
#include <math.h>

#define TPB 256

using v4 = __attribute__((ext_vector_type(4))) float;

__global__ __launch_bounds__(TPB) void geo_kernel(const float* __restrict__ coords,
                                                  float* __restrict__ out, int n) {
    // Input window: floats [3*base-4, 3*base+772) -> 776 floats, 16B-aligned
    // since 3*base = 768*blockIdx. Local index of global float f = f-(3*base-4).
    __shared__ float s_c[780];
    __shared__ float s_ang[TPB * 3];   // 3 KB
    __shared__ float s_frm[TPB * 9];   // 9 KB

    const int tid  = threadIdx.x;
    const int base = blockIdx.x * TPB;
    const int r    = base + tid;

    if (blockIdx.x > 0 && blockIdx.x + 1 < gridDim.x) {
        // interior: one aligned float4 per thread (194 total)
        const v4* g4 = (const v4*)(coords + (3L * base - 4));
        v4* s4 = (v4*)s_c;
        if (tid < 194) s4[tid] = g4[tid];
    } else {
        // edge blocks: clamped scalar staging (clamped floats are never read)
        const long gmax = 3L * n - 1;
        for (int i = tid; i < 776; i += TPB) {
            long g = 3L * base - 4 + i;
            g = g < 0 ? 0 : (g > gmax ? gmax : g);
            s_c[i] = coords[g];
        }
    }
    __syncthreads();

    if (r < n) {
        // frame row: rows 0 / n-1 duplicate rows 1 / n-2
        int rr = r < 1 ? 1 : (r > n - 2 ? n - 2 : r);
        const float* p = s_c + 3 * (rr - base) + 1;  // floats of rows rr-1..rr+1

        float d1x = p[3] - p[0], d1y = p[4] - p[1], d1z = p[5] - p[2];
        float d2x = p[6] - p[3], d2y = p[7] - p[4], d2z = p[8] - p[5];

        float inv1 = __builtin_amdgcn_rsqf(d1x * d1x + d1y * d1y + d1z * d1z + 1e-20f);
        float v1x = d1x * inv1, v1y = d1y * inv1, v1z = d1z * inv1;

        float inv2 = __builtin_amdgcn_rsqf(d2x * d2x + d2y * d2y + d2z * d2z + 1e-20f);
        float v2x = d2x * inv2, v2y = d2y * inv2, v2z = d2z * inv2;

        float dotv   = v1x * v2x + v1y * v2y + v1z * v2z;
        float cosang = fminf(1.0f, fmaxf(-1.0f, dotv));

        // acos via A&S 4.4.45: acos(x) ~ sqrt(1-x)*poly(x); |err| < 6.7e-5
        float ax   = fabsf(cosang);
        float sq   = __builtin_amdgcn_sqrtf(1.0f - ax);
        float poly = 1.5707288f + ax * (-0.2121144f + ax * (0.0742610f + ax * (-0.0187293f)));
        float rpos = sq * poly;
        float ang  = cosang >= 0.0f ? rpos : (3.14159265358979f - rpos);
        if (r == 0 || r == n - 1) ang = 0.0f;

        // Gram-Schmidt (proj uses UNclamped dot, matching the reference)
        float tx = v2x - dotv * v1x, ty = v2y - dotv * v1y, tz = v2z - dotv * v1z;
        float invt = __builtin_amdgcn_rsqf(tx * tx + ty * ty + tz * tz + 1e-20f);
        float e2x = tx * invt, e2y = ty * invt, e2z = tz * invt;

        float e3x = v1y * e2z - v1z * e2y;
        float e3y = v1z * e2x - v1x * e2z;
        float e3z = v1x * e2y - v1y * e2x;

        s_ang[tid * 3 + 0] = ang;
        s_ang[tid * 3 + 1] = ang;
        s_ang[tid * 3 + 2] = ang;

        float* f = s_frm + tid * 9;
        f[0] = v1x; f[1] = v1y; f[2] = v1z;
        f[3] = e2x; f[4] = e2y; f[5] = e2z;
        f[6] = e3x; f[7] = e3y; f[8] = e3z;
    }
    __syncthreads();

    float* angles = out;                     // n*3 floats
    float* frames = out + (size_t)n * 3;     // n*9 floats

    int valid = n - base;
    if (valid > TPB) valid = TPB;

    if (valid == TPB) {
        // plain coalesced float4 flush (nt reverted); block offsets 16B-aligned
        v4*       ga = (v4*)(angles + (size_t)base * 3);
        const v4* sa = (const v4*)s_ang;
        if (tid < (TPB * 3) / 4) ga[tid] = sa[tid];          // 192 x float4

        v4*       gf = (v4*)(frames + (size_t)base * 9);
        const v4* sf = (const v4*)s_frm;
        gf[tid]       = sf[tid];                             // 576 x float4
        gf[tid + 256] = sf[tid + 256];
        if (tid < 64) gf[tid + 512] = sf[tid + 512];
    } else {
        if (r < n) {
            angles[(size_t)r * 3 + 0] = s_ang[tid * 3 + 0];
            angles[(size_t)r * 3 + 1] = s_ang[tid * 3 + 1];
            angles[(size_t)r * 3 + 2] = s_ang[tid * 3 + 2];
            for (int k = 0; k < 9; ++k)
                frames[(size_t)r * 9 + k] = s_frm[tid * 9 + k];
        }
    }
}

extern "C" void kernel_launch(void* const* d_in, const int* in_sizes, int n_in,
                              void* d_out, int out_size, void* d_ws, size_t ws_size,
                              hipStream_t stream) {
    const float* coords = (const float*)d_in[0];
    float*       out    = (float*)d_out;
    int n = in_sizes[0] / 3;
    int blocks = (n + TPB - 1) / TPB;
    hipLaunchKernelGGL(geo_kernel, dim3(blocks), dim3(TPB), 0, stream, coords, out, n);
}